// Round 1
// 1659.102 us; speedup vs baseline: 1.2103x; 1.2103x over previous
//
#include <hip/hip_runtime.h>

// Swin block, MI355X gfx950. Global I/O fp32 (per reference); internal GEMMs
// bf16 via v_mfma_f32_16x16x32_bf16 with fp32 accumulation.
// Pipeline per batch-slice:
//   K0 cvt_weights : qkv_w/proj_w/w1/w2 fp32 -> bf16 in ws (once per call)
//   K1 attn_fused  : x -> x2 = x + proj(attn(LN1(x))), xln = LN2(x2)
//                    [block = 8x8 window; 3 barriers total; q in regs;
//                     XOR-swizzled LDS, 54.3 KB -> 3 blocks/CU]
//   K2 mlp1_gemm   : xln -> mh = gelu(xln @ w1^T + b1)  (pure GEMM, 1 dispatch)
//   K3 gemm_bt     : out = mh @ w2^T + b2 + x2          (K=768 single pass)

typedef short s8v __attribute__((ext_vector_type(8)));
typedef float f4v __attribute__((ext_vector_type(4)));
typedef unsigned short u16;

static __device__ __forceinline__ float b2f(u16 u) {
    unsigned int x = ((unsigned int)u) << 16;
    return __builtin_bit_cast(float, x);
}
static __device__ __forceinline__ u16 f2b(float f) {
    unsigned int u = __builtin_bit_cast(unsigned int, f);
    u = (u + 0x7FFF + ((u >> 16) & 1)) >> 16;   // RNE
    return (u16)u;
}
static __device__ __forceinline__ f4v mfma16(s8v a, s8v b, f4v c) {
    return __builtin_amdgcn_mfma_f32_16x16x32_bf16(a, b, c, 0, 0, 0);
}

// XOR swizzle: flip elem-index bits 3..5 with (row&7). Row bases of all tiles
// are 0 mod 64 elems, reads are 8-elem chunks -> bijective, 16B-aligned, and
// spreads stride-192/stride-64 row-major column reads evenly over banks.
#define SWZ(r, e) ((e) ^ (((r) & 7) << 3))

// sizes (elems) of the 4 weight matrices and their bf16 ws offsets
#define SZ_QKV  110592   // 576 x 192
#define SZ_PROJ  36864   // 192 x 192
#define SZ_W1   147456   // 768 x 192
#define SZ_W2   147456   // 192 x 768
#define OFF_PROJ (SZ_QKV)
#define OFF_W1   (SZ_QKV + SZ_PROJ)
#define OFF_W2   (SZ_QKV + SZ_PROJ + SZ_W1)
#define W_TOTAL  (SZ_QKV + SZ_PROJ + SZ_W1 + SZ_W2)   // 442368

// =============== K0: weight fp32 -> bf16 =====================================
__global__ __launch_bounds__(256) void cvt_weights(
    const float* __restrict__ qkv_w, const float* __restrict__ proj_w,
    const float* __restrict__ w1, const float* __restrict__ w2,
    u16* __restrict__ dst)
{
    int i4 = (blockIdx.x * 256 + threadIdx.x) * 4;
    const float* src; int off;
    if (i4 < OFF_PROJ)     { src = qkv_w; off = i4; }
    else if (i4 < OFF_W1)  { src = proj_w; off = i4 - OFF_PROJ; }
    else if (i4 < OFF_W2)  { src = w1; off = i4 - OFF_W1; }
    else                   { src = w2; off = i4 - OFF_W2; }
    float4 v = *(const float4*)(src + off);
    ushort4 o;
    o.x = f2b(v.x); o.y = f2b(v.y); o.z = f2b(v.z); o.w = f2b(v.w);
    *(ushort4*)(dst + i4) = o;
}

// =============== K1: fused LN1 + QKV + window-attention + proj + resid + LN2 =
__global__ __launch_bounds__(256, 3) void attn_fused(
    const float* __restrict__ x, const u16* __restrict__ Wqkv,
    const float* __restrict__ bqkv, const u16* __restrict__ Wproj,
    const float* __restrict__ bproj, const float* __restrict__ g1,
    const float* __restrict__ bn1, const float* __restrict__ g2,
    const float* __restrict__ bn2, u16* __restrict__ x2,
    u16* __restrict__ xln)
{
    __shared__ __align__(16) u16 lds[27136];   // 54272 B -> 3 blocks/CU
    u16* hs   = lds;           // 64 x 192 swz (LN1 tokens); dead after frag load
    u16* ks   = lds;           // ALIASES hs: 64 x 192 swz (l2norm'd k)
    u16* vt   = lds + 12288;   // 192 x 64 swz (v transposed [dim][token])
    u16* pscr = lds + 24576;   // 4 waves x 16 x 40 wave-private scratch

    const int tid = threadIdx.x;
    const int wv = tid >> 6, lane = tid & 63;
    const int lr = lane & 15, lq = lane >> 4;
    const int wloc = blockIdx.x;
    const int bb = wloc >> 8, wh = (wloc >> 4) & 15, ww = wloc & 15;
    u16* pw = pscr + wv * 640;

    // ---- LN1 stage (single pass; x kept in registers) ----
    {
        int tk = tid >> 2, q4 = tid & 3;
        int gh = (wh * 8 + (tk >> 3) + 4) & 127;
        int gw = (ww * 8 + (tk & 7) + 4) & 127;
        const float* xr = x + (((size_t)bb * 128 + gh) * 128 + gw) * 192 + q4 * 48;
        float4 xv[12];
        float s = 0.f, sq = 0.f;
#pragma unroll
        for (int i = 0; i < 12; i++) {
            xv[i] = *(const float4*)(xr + i * 4);
            s += xv[i].x + xv[i].y + xv[i].z + xv[i].w;
            sq += xv[i].x * xv[i].x + xv[i].y * xv[i].y
                + xv[i].z * xv[i].z + xv[i].w * xv[i].w;
        }
        s += __shfl_xor(s, 1); sq += __shfl_xor(sq, 1);
        s += __shfl_xor(s, 2); sq += __shfl_xor(sq, 2);
        float mean = s * (1.0f / 192.0f);
        float var = sq * (1.0f / 192.0f) - mean * mean;
        float rstd = 1.0f / sqrtf(var + 1e-5f);
#pragma unroll
        for (int i = 0; i < 12; i += 2) {
            int c0 = q4 * 48 + i * 4;
            float4 ga  = *(const float4*)(g1 + c0);
            float4 gb  = *(const float4*)(g1 + c0 + 4);
            float4 ba  = *(const float4*)(bn1 + c0);
            float4 bbv = *(const float4*)(bn1 + c0 + 4);
            s8v ov;
            ov[0] = (short)f2b((xv[i].x - mean) * rstd * ga.x + ba.x);
            ov[1] = (short)f2b((xv[i].y - mean) * rstd * ga.y + ba.y);
            ov[2] = (short)f2b((xv[i].z - mean) * rstd * ga.z + ba.z);
            ov[3] = (short)f2b((xv[i].w - mean) * rstd * ga.w + ba.w);
            ov[4] = (short)f2b((xv[i + 1].x - mean) * rstd * gb.x + bbv.x);
            ov[5] = (short)f2b((xv[i + 1].y - mean) * rstd * gb.y + bbv.y);
            ov[6] = (short)f2b((xv[i + 1].z - mean) * rstd * gb.z + bbv.z);
            ov[7] = (short)f2b((xv[i + 1].w - mean) * rstd * gb.w + bbv.w);
            *(s8v*)&hs[SWZ(tk, tk * 192 + c0)] = ov;
        }
    }
    __syncthreads();                       // barrier 1: hs complete

    const int trow = 16 * wv + lr;
    s8v af[6];
#pragma unroll
    for (int k = 0; k < 6; k++)
        af[k] = *(const s8v*)&hs[SWZ(trow, trow * 192 + 32 * k + lq * 8)];
    __syncthreads();                       // barrier 2: hs region free -> ks

    // ---- QKV phase (all 6 heads, no barriers): q->regs, k->ks, v->vt ----
    s8v aq[6];
#pragma unroll
    for (int h = 0; h < 6; h++) {
        f4v acc[6] = {};
#pragma unroll
        for (int k = 0; k < 6; k++) {
#pragma unroll
            for (int n = 0; n < 6; n++) {
                int wr = (n < 2) ? (32 * h + 16 * n + lr)
                       : (n < 4) ? (192 + 32 * h + 16 * (n - 2) + lr)
                                 : (384 + 32 * h + 16 * (n - 4) + lr);
                s8v bf = *(const s8v*)&Wqkv[(size_t)wr * 192 + 32 * k + lq * 8];
                acc[n] = mfma16(af[k], bf, acc[n]);
            }
        }
        float bq0 = bqkv[32 * h + lr],       bq1 = bqkv[32 * h + 16 + lr];
        float bk0 = bqkv[192 + 32 * h + lr], bk1 = bqkv[192 + 32 * h + 16 + lr];
        float bv0 = bqkv[384 + 32 * h + lr], bv1 = bqkv[384 + 32 * h + 16 + lr];
#pragma unroll
        for (int reg = 0; reg < 4; reg++) {
            int row = 16 * wv + lq * 4 + reg;
            float q0 = acc[0][reg] + bq0, q1 = acc[1][reg] + bq1;
            float ss = q0 * q0 + q1 * q1;
#pragma unroll
            for (int m = 1; m < 16; m <<= 1) ss += __shfl_xor(ss, m);
            float inv = 1.0f / fmaxf(sqrtf(ss), 1e-12f);
            pw[(lq * 4 + reg) * 40 + lr]      = f2b(q0 * inv);
            pw[(lq * 4 + reg) * 40 + 16 + lr] = f2b(q1 * inv);

            float k0v = acc[2][reg] + bk0, k1v = acc[3][reg] + bk1;
            ss = k0v * k0v + k1v * k1v;
#pragma unroll
            for (int m = 1; m < 16; m <<= 1) ss += __shfl_xor(ss, m);
            inv = 1.0f / fmaxf(sqrtf(ss), 1e-12f);
            ks[SWZ(row, row * 192 + 32 * h + lr)]      = f2b(k0v * inv);
            ks[SWZ(row, row * 192 + 32 * h + 16 + lr)] = f2b(k1v * inv);

            int d0 = 32 * h + lr, d1 = 32 * h + 16 + lr;
            vt[SWZ(d0, d0 * 64 + row)] = f2b(acc[4][reg] + bv0);
            vt[SWZ(d1, d1 * 64 + row)] = f2b(acc[5][reg] + bv1);
        }
        aq[h] = *(const s8v*)&pw[lr * 40 + lq * 8];   // q A-frag to regs
    }
    __syncthreads();                       // barrier 3: ks/vt published

    // ---- attention loop: ZERO barriers (only wave-private scratch reuse) ----
    f4v acc2[12] = {};
    const float scale = 0.17677669529663687f;   // 32^-0.5
#pragma unroll
    for (int h = 0; h < 6; h++) {
        f4v accS[4] = {};
#pragma unroll
        for (int j = 0; j < 4; j++) {
            int kr = 16 * j + lr;
            s8v bk = *(const s8v*)&ks[SWZ(kr, kr * 192 + 32 * h + lq * 8)];
            accS[j] = mfma16(aq[h], bk, accS[j]);
        }
        float p[4][4];
#pragma unroll
        for (int reg = 0; reg < 4; reg++) {
            float v0 = accS[0][reg] * scale, v1 = accS[1][reg] * scale;
            float v2 = accS[2][reg] * scale, v3 = accS[3][reg] * scale;
            float mx = fmaxf(fmaxf(v0, v1), fmaxf(v2, v3));
#pragma unroll
            for (int m = 1; m < 16; m <<= 1) mx = fmaxf(mx, __shfl_xor(mx, m));
            float e0 = __expf(v0 - mx), e1 = __expf(v1 - mx);
            float e2 = __expf(v2 - mx), e3 = __expf(v3 - mx);
            float sum = e0 + e1 + e2 + e3;
#pragma unroll
            for (int m = 1; m < 16; m <<= 1) sum += __shfl_xor(sum, m);
            float is = 1.0f / sum;
            p[0][reg] = fminf(fmaxf(e0 * is, 1e-6f), 1.0f);
            p[1][reg] = fminf(fmaxf(e1 * is, 1e-6f), 1.0f);
            p[2][reg] = fminf(fmaxf(e2 * is, 1e-6f), 1.0f);
            p[3][reg] = fminf(fmaxf(e3 * is, 1e-6f), 1.0f);
        }
        // P -> bf16 A-frags in two 32-col halves through wave-private scratch
        f4v accO[2] = {};
#pragma unroll
        for (int reg = 0; reg < 4; reg++) {
            pw[(lq * 4 + reg) * 40 + lr]      = f2b(p[0][reg]);
            pw[(lq * 4 + reg) * 40 + 16 + lr] = f2b(p[1][reg]);
        }
        {
            s8v ap0 = *(const s8v*)&pw[lr * 40 + lq * 8];
#pragma unroll
            for (int n = 0; n < 2; n++) {
                int d = 32 * h + 16 * n + lr;
                s8v bvf = *(const s8v*)&vt[SWZ(d, d * 64 + lq * 8)];
                accO[n] = mfma16(ap0, bvf, accO[n]);
            }
        }
#pragma unroll
        for (int reg = 0; reg < 4; reg++) {
            pw[(lq * 4 + reg) * 40 + lr]      = f2b(p[2][reg]);
            pw[(lq * 4 + reg) * 40 + 16 + lr] = f2b(p[3][reg]);
        }
        {
            s8v ap1 = *(const s8v*)&pw[lr * 40 + lq * 8];
#pragma unroll
            for (int n = 0; n < 2; n++) {
                int d = 32 * h + 16 * n + lr;
                s8v bvf = *(const s8v*)&vt[SWZ(d, d * 64 + 32 + lq * 8)];
                accO[n] = mfma16(ap1, bvf, accO[n]);
            }
        }
        // O transpose via scratch; accumulate proj
#pragma unroll
        for (int n = 0; n < 2; n++)
#pragma unroll
            for (int reg = 0; reg < 4; reg++)
                pw[(lq * 4 + reg) * 40 + 16 * n + lr] = f2b(accO[n][reg]);
        s8v apj = *(const s8v*)&pw[lr * 40 + lq * 8];
#pragma unroll
        for (int n = 0; n < 12; n++) {
            s8v bpj = *(const s8v*)&Wproj[(size_t)(16 * n + lr) * 192 + 32 * h + lq * 8];
            acc2[n] = mfma16(apj, bpj, acc2[n]);
        }
    }

    // ---- epilogue: x2 = proj + bias + x (roll(+4) scatter); fused LN2 ----
    float bpv[12], g2v[12], b2v[12];
#pragma unroll
    for (int n = 0; n < 12; n++) {
        int col = 16 * n + lr;
        bpv[n] = bproj[col]; g2v[n] = g2[col]; b2v[n] = bn2[col];
    }
#pragma unroll
    for (int reg = 0; reg < 4; reg++) {
        int tk = 16 * wv + lq * 4 + reg;
        int gh = (wh * 8 + (tk >> 3) + 4) & 127;
        int gw = (ww * 8 + (tk & 7) + 4) & 127;
        size_t base = (((size_t)bb * 128 + gh) * 128 + gw) * 192;
        float vv[12];
        float s = 0.f, sq = 0.f;
#pragma unroll
        for (int n = 0; n < 12; n++) {
            float v = acc2[n][reg] + bpv[n] + x[base + 16 * n + lr];
            vv[n] = v; s += v; sq += v * v;
        }
        s += __shfl_xor(s, 1); sq += __shfl_xor(sq, 1);
        s += __shfl_xor(s, 2); sq += __shfl_xor(sq, 2);
        s += __shfl_xor(s, 4); sq += __shfl_xor(sq, 4);
        s += __shfl_xor(s, 8); sq += __shfl_xor(sq, 8);
        float mean = s * (1.0f / 192.0f);
        float var = sq * (1.0f / 192.0f) - mean * mean;
        float rstd = 1.0f / sqrtf(var + 1e-5f);
#pragma unroll
        for (int n = 0; n < 12; n++) {
            size_t idx = base + 16 * n + lr;
            x2[idx]  = f2b(vv[n]);
            xln[idx] = f2b((vv[n] - mean) * rstd * g2v[n] + b2v[n]);
        }
    }
}

// =============== K2: MLP GEMM1 (pure GEMM on precomputed LN2) + gelu =========
// nchunk output chunks of 192 cols computed from ONE staged A-tile.
__global__ __launch_bounds__(256, 3) void mlp1_gemm(
    const u16* __restrict__ xln, const u16* __restrict__ W1,
    const float* __restrict__ B1, u16* __restrict__ mh, int ldm, int nchunk)
{
    __shared__ __align__(16) u16 As[128 * 200];   // 51200 B -> 3 blocks/CU
    const int tid = threadIdx.x;
    const int wv = tid >> 6, lane = tid & 63;
    const int lr = lane & 15, lq = lane >> 4;
    const size_t m0 = (size_t)blockIdx.x * 128;

    {   // stage 128 x 192 (straight copy, no LN)
        int r = tid >> 1, hf = tid & 1;
        const u16* xr = xln + (m0 + r) * 192 + hf * 96;
        u16* ar = As + r * 200 + hf * 96;
#pragma unroll
        for (int i = 0; i < 12; i++)
            *(s8v*)(ar + i * 8) = *(const s8v*)(xr + i * 8);
    }
    __syncthreads();

    for (int c = 0; c < nchunk; c++) {
        f4v acc[2][12] = {};
        for (int k0 = 0; k0 < 192; k0 += 32) {
            s8v afr[2];
#pragma unroll
            for (int mt = 0; mt < 2; mt++)
                afr[mt] = *(const s8v*)&As[(32 * wv + 16 * mt + lr) * 200 + k0 + lq * 8];
#pragma unroll
            for (int n = 0; n < 12; n++) {
                s8v bf = *(const s8v*)&W1[(size_t)(c * 192 + 16 * n + lr) * 192 + k0 + lq * 8];
#pragma unroll
                for (int mt = 0; mt < 2; mt++)
                    acc[mt][n] = mfma16(afr[mt], bf, acc[mt][n]);
            }
        }
#pragma unroll
        for (int n = 0; n < 12; n++) {
            int col = c * 192 + 16 * n + lr;
            float bb = B1[col];
#pragma unroll
            for (int mt = 0; mt < 2; mt++)
#pragma unroll
                for (int reg = 0; reg < 4; reg++) {
                    size_t row = m0 + 32 * wv + 16 * mt + lq * 4 + reg;
                    float v = acc[mt][n][reg] + bb;
                    v = 0.5f * v * (1.0f + erff(v * 0.70710678118654752f));
                    mh[row * ldm + col] = f2b(v);
                }
        }
    }
}

// =============== K3: GEMM C = A @ W^T (+bias)(+resid), out fp32 ==============
// RES: 0 none, 1 resid bf16, 2 resid fp32
#define BM 128
#define BN 64
#define LDT 40

template <int RES>
__global__ __launch_bounds__(256) void gemm_bt(
    const u16* __restrict__ A, int lda,
    const u16* __restrict__ W, int ldb,
    const float* __restrict__ bias,
    const u16* __restrict__ residB, const float* __restrict__ residF, int ldr,
    float* __restrict__ Cout, int ldc, int K)
{
    __shared__ __align__(16) u16 As[BM * LDT];
    __shared__ __align__(16) u16 Bs[BN * LDT];
    const int tid = threadIdx.x;
    const int wave = tid >> 6, lane = tid & 63;
    const int lr = lane & 15, lq = lane >> 4;
    const int wm = (wave >> 1) * 64;
    const int wn = (wave & 1) * 32;
    const size_t m0 = (size_t)blockIdx.y * BM;
    const int n0 = blockIdx.x * BN;

    const int ar = tid >> 1, ac = (tid & 1) * 16;
    const int br = tid >> 2, bc = (tid & 3) * 8;
    const u16* aptr = A + (m0 + ar) * (size_t)lda + ac;
    const u16* bptr = W + (size_t)(n0 + br) * ldb + bc;

    f4v acc[4][2] = {};
    for (int k0 = 0; k0 < K; k0 += 32) {
        __syncthreads();
        *(s8v*)&As[ar * LDT + ac]     = *(const s8v*)(aptr + k0);
        *(s8v*)&As[ar * LDT + ac + 8] = *(const s8v*)(aptr + k0 + 8);
        *(s8v*)&Bs[br * LDT + bc]     = *(const s8v*)(bptr + k0);
        __syncthreads();
        s8v af[4], bfr[2];
#pragma unroll
        for (int mt = 0; mt < 4; mt++)
            af[mt] = *(const s8v*)&As[(wm + mt * 16 + lr) * LDT + lq * 8];
#pragma unroll
        for (int nt = 0; nt < 2; nt++)
            bfr[nt] = *(const s8v*)&Bs[(wn + nt * 16 + lr) * LDT + lq * 8];
#pragma unroll
        for (int mt = 0; mt < 4; mt++)
#pragma unroll
            for (int nt = 0; nt < 2; nt++)
                acc[mt][nt] = mfma16(af[mt], bfr[nt], acc[mt][nt]);
    }

    float bv[2];
#pragma unroll
    for (int nt = 0; nt < 2; nt++) {
        int col = n0 + wn + nt * 16 + lr;
        bv[nt] = bias ? bias[col] : 0.0f;
    }
#pragma unroll
    for (int mt = 0; mt < 4; mt++)
#pragma unroll
        for (int reg = 0; reg < 4; reg++) {
            size_t row = m0 + wm + mt * 16 + lq * 4 + reg;
#pragma unroll
            for (int nt = 0; nt < 2; nt++) {
                int col = n0 + wn + nt * 16 + lr;
                float v = acc[mt][nt][reg] + bv[nt];
                if (RES == 1) v += b2f(residB[row * (size_t)ldr + col]);
                if (RES == 2) v += residF[row * (size_t)ldr + col];
                Cout[row * (size_t)ldc + col] = v;
            }
        }
}

// ---------------- driver -----------------------------------------------------
extern "C" void kernel_launch(void* const* d_in, const int* in_sizes, int n_in,
                              void* d_out, int out_size, void* d_ws, size_t ws_size,
                              hipStream_t stream) {
    const float* x      = (const float*)d_in[0];
    const float* qkv_w  = (const float*)d_in[1];
    const float* qkv_b  = (const float*)d_in[2];
    const float* proj_w = (const float*)d_in[3];
    const float* proj_b = (const float*)d_in[4];
    const float* n1_g   = (const float*)d_in[5];
    const float* n1_b   = (const float*)d_in[6];
    const float* n2_g   = (const float*)d_in[7];
    const float* n2_b   = (const float*)d_in[8];
    const float* w1     = (const float*)d_in[9];
    const float* b1     = (const float*)d_in[10];
    const float* w2     = (const float*)d_in[11];
    const float* b2     = (const float*)d_in[12];
    float* out = (float*)d_out;

    u16* wsu = (u16*)d_ws;
    u16* wQ  = wsu;
    u16* wP  = wsu + OFF_PROJ;
    u16* wW1 = wsu + OFF_W1;
    u16* wW2 = wsu + OFF_W2;
    char* dataBase = (char*)d_ws + (1 << 20);
    size_t avail = (ws_size > (1 << 20)) ? ws_size - (1 << 20) : 0;

    dim3 blk(256);
    cvt_weights<<<W_TOTAL / 1024, blk, 0, stream>>>(qkv_w, proj_w, w1, w2, wsu);

    // largest Bs with x2 + xln (Ts x 192 each) + mh (Ts x 768) bf16 in ws
    const size_t perTok = (size_t)(192 + 192 + 768) * 2;
    int Bs = 16;
    while (Bs > 1 && (size_t)Bs * 16384 * perTok > avail) Bs >>= 1;
    const bool bigHC = ((size_t)Bs * 16384 * perTok <= avail);

    if (bigHC) {
        const int nslice = 16 / Bs;
        const size_t stok = (size_t)Bs * 16384;
        u16* x2buf  = (u16*)dataBase;
        u16* xlnbuf = x2buf + stok * 192;
        u16* mhbuf  = xlnbuf + stok * 192;
        for (int s = 0; s < nslice; s++) {
            const float* xs = x + (size_t)s * stok * 192;
            float* outs = out + (size_t)s * stok * 192;
            attn_fused<<<Bs * 256, blk, 0, stream>>>(xs, wQ, qkv_b, wP, proj_b,
                                                     n1_g, n1_b, n2_g, n2_b,
                                                     x2buf, xlnbuf);
            mlp1_gemm<<<Bs * 128, blk, 0, stream>>>(xlnbuf, wW1, b1, mhbuf, 768, 4);
            gemm_bt<1><<<dim3(3, Bs * 128), blk, 0, stream>>>(
                mhbuf, 768, wW2, 768, b2, x2buf, nullptr, 192, outs, 192, 768);
        }
    } else {
        // tiny-ws fallback: Bs=1, hidden chunked at 192, out accumulated fp32
        const size_t stok = 16384;
        u16* x2buf  = (u16*)dataBase;
        u16* xlnbuf = x2buf + stok * 192;
        u16* mhbuf  = xlnbuf + stok * 192;
        for (int s = 0; s < 16; s++) {
            const float* xs = x + (size_t)s * stok * 192;
            float* outs = out + (size_t)s * stok * 192;
            attn_fused<<<256, blk, 0, stream>>>(xs, wQ, qkv_b, wP, proj_b,
                                                n1_g, n1_b, n2_g, n2_b,
                                                x2buf, xlnbuf);
            for (int c = 0; c < 4; c++) {
                mlp1_gemm<<<128, blk, 0, stream>>>(
                    xlnbuf, wW1 + (size_t)c * 192 * 192, b1 + c * 192,
                    mhbuf, 192, 1);
                if (c == 0)
                    gemm_bt<1><<<dim3(3, 128), blk, 0, stream>>>(
                        mhbuf, 192, wW2 + c * 192, 768, b2,
                        x2buf, nullptr, 192, outs, 192, 192);
                else
                    gemm_bt<2><<<dim3(3, 128), blk, 0, stream>>>(
                        mhbuf, 192, wW2 + c * 192, 768, nullptr,
                        nullptr, outs, 192, outs, 192, 192);
            }
        }
    }
}